// Round 1
// baseline (103.564 us; speedup 1.0000x reference)
//
#include <hip/hip_runtime.h>
#include <hip/hip_cooperative_groups.h>
#include <math.h>

#define TWO_PI 6.283185307179586f

namespace cg = cooperative_groups;

// out-row DHT: sum_{m<64} zr[m] * cas(2*pi*m*k/4097), m = 8a+b split with
// one sincos per k, incremental weights, 8-step rotator (verbatim kC math).
__device__ __forceinline__ float dht4097_row(const float* zr, int k) {
  const float th = (float)k * (TWO_PI / 4097.0f);
  float s1, c1;
  __sincosf(th, &s1, &c1);
  float cw[8], sw[8];
  cw[0] = 1.0f; sw[0] = 0.0f;
  cw[1] = c1;   sw[1] = s1;
#pragma unroll
  for (int b = 2; b < 8; ++b) {
    cw[b] = cw[b - 1] * c1 - sw[b - 1] * s1;
    sw[b] = sw[b - 1] * c1 + cw[b - 1] * s1;
  }
  const float c8 = cw[7] * c1 - sw[7] * s1;
  const float s8 = sw[7] * c1 + cw[7] * s1;
  float A[8], B[8];
#pragma unroll
  for (int b = 0; b < 8; ++b) { A[b] = 0.0f; B[b] = 0.0f; }
  float u = 1.0f, v = 1.0f;
#pragma unroll
  for (int a = 0; a < 8; ++a) {
#pragma unroll
    for (int b = 0; b < 8; ++b) {
      const float zz = zr[a * 8 + b];
      A[b] += zz * u;
      B[b] += zz * v;
    }
    const float un = c8 * u + s8 * v;
    const float vn = c8 * v - s8 * u;
    u = un; v = vn;
  }
  float acc = 0.0f;
#pragma unroll
  for (int b = 0; b < 8; ++b) acc += cw[b] * A[b] + sw[b] * B[b];
  return acc;
}

// ---------------------------------------------------------------------------
// Single cooperative kernel, 256 blocks x 256 threads (1 block/CU):
//   phase 1: kA verbatim -> P[r][m][nh] partials in workspace
//   grid.sync()
//   phase 2: kB for ALL 4 m-quarters of row (blk&63); z row stays in LDS
//   phase 3: kC for this row, k-quarter (blk>>6): 4 outputs/thread
// Rationale: compute is ~3us total; the 3-kernel version paid 2 extra
// dispatch-boundary drains + a z global round-trip (~launch-bound).
// ---------------------------------------------------------------------------
__global__ __launch_bounds__(256) void fused(const float* __restrict__ x,
                                             const float* __restrict__ w1,
                                             float* __restrict__ out,
                                             float* __restrict__ P) {
  __shared__ float sH[128], cH[128], sL[64], cL[64];
  __shared__ float sA[16][64];
  __shared__ float sW[16][64];
  __shared__ float zrow[64];

  const int blk = blockIdx.x;
  const int t = threadIdx.x;

  // ---------------- phase 1: big-DHT partials (== kA) ----------------------
  if (t < 128) {
    float s, c;
    __sincosf((float)t * (TWO_PI / 128.0f), &s, &c);
    sH[t] = s;
    cH[t] = c;
  } else if (t < 192) {
    const int g = t - 128;
    float s, c;
    __sincosf((float)g * (TWO_PI / 8192.0f), &s, &c);
    sL[g] = s;
    cL[g] = c;
  }
  __syncthreads();

  {
    const int r  = blk & 63;
    const int mb = (blk >> 6) & 1;
    const int nh = (blk >> 7) & 1;
    const int l  = t & 63;
    const int w  = t >> 6;
    const int mbase = mb * 32 + w * 8;
    const float* xr = x + r * 8192 + nh * 4096;

    float u[8], v[8], Cs[8], Ss[8];
    float accA[8][4];
    float accB[8][3];

#pragma unroll
    for (int q = 0; q < 8; ++q) {
      const int m = mbase + q;
      const int idx0 = ((nh * 4096 + 4 * l) * m) & 8191;
      const int h = idx0 >> 6, g = idx0 & 63;
      const float c0 = cH[h] * cL[g] - sH[h] * sL[g];
      const float s0 = sH[h] * cL[g] + cH[h] * sL[g];
      u[q] = c0 + s0;
      v[q] = c0 - s0;
      const int ih = (4 * m) & 127;  // 256*m mod 8192 lands on the hi table
      Cs[q] = cH[ih];
      Ss[q] = sH[ih];
#pragma unroll
      for (int j = 0; j < 4; ++j) accA[q][j] = 0.0f;
#pragma unroll
      for (int j = 0; j < 3; ++j) accB[q][j] = 0.0f;
    }

#pragma unroll 8
    for (int it = 0; it < 16; ++it) {
      const float4 xv = *reinterpret_cast<const float4*>(xr + it * 256 + 4 * l);
#pragma unroll
      for (int q = 0; q < 8; ++q) {
        accA[q][0] += xv.x * u[q];
        accA[q][1] += xv.y * u[q];
        accA[q][2] += xv.z * u[q];
        accA[q][3] += xv.w * u[q];
        accB[q][0] += xv.y * v[q];
        accB[q][1] += xv.z * v[q];
        accB[q][2] += xv.w * v[q];
        const float un = Cs[q] * u[q] + Ss[q] * v[q];
        const float vn = Cs[q] * v[q] - Ss[q] * u[q];
        u[q] = un;
        v[q] = vn;
      }
    }

    // combine weights cos(j*m*step), sin(j*m*step): lane (q*4+j) computes.
    float cval, sval;
    {
      const int qq = (l >> 2) & 7;
      const int jj = l & 3;
      const int jm = jj * (mbase + qq);  // <= 189 < 8192
      const int h = jm >> 6, g = jm & 63;
      cval = cH[h] * cL[g] - sH[h] * sL[g];
      sval = sH[h] * cL[g] + cH[h] * sL[g];
    }

#pragma unroll
    for (int q = 0; q < 8; ++q) {
      float acc = accA[q][0];
#pragma unroll
      for (int j = 1; j < 4; ++j) {
        const float cj = __shfl(cval, q * 4 + j, 64);
        const float sj = __shfl(sval, q * 4 + j, 64);
        acc += cj * accA[q][j] + sj * accB[q][j - 1];
      }
#pragma unroll
      for (int off = 32; off > 0; off >>= 1) acc += __shfl_xor(acc, off, 64);
      if (l == q) P[(r * 64 + (mbase + q)) * 2 + nh] = acc;
    }
  }

  cg::this_grid().sync();

  // ---------------- phase 2: conv theorem (== kB, all 4 quarters) ----------
  // z[b,o,m] = (1/64) * sum_i sum_j A[b,i,j] * w1[i,o,(m-j)&63]; z in LDS.
  const int row = blk & 63;   // b*16 + o
  const int kq  = blk >> 6;   // this block's k-quarter for phase 3
  const int b   = row >> 4;
  const int o   = row & 15;

  for (int idx = t; idx < 1024; idx += 256) {
    const int i = idx >> 6;
    const int c = idx & 63;
    const float2 pv =
        *reinterpret_cast<const float2*>(&P[(((b * 16 + i) << 6) + c) * 2]);
    sA[i][c] = pv.x + pv.y;
    sW[i][c] = w1[((i * 16 + o) << 6) + c];
  }
  __syncthreads();

  {
    const int w  = t >> 6;    // wave = m-quarter
    const int l  = t & 63;
    const int jq = l >> 4;    // j-quarter
    const int ml = l & 15;    // local m
    const int m  = w * 16 + ml;
    float acc = 0.0f;
#pragma unroll
    for (int i = 0; i < 16; ++i) {
#pragma unroll
      for (int jb = 0; jb < 4; ++jb) {
        const int j0 = jq * 16 + jb * 4;
        const float4 a4 = *reinterpret_cast<const float4*>(&sA[i][j0]);
        acc += a4.x * sW[i][(m - j0) & 63];
        acc += a4.y * sW[i][(m - j0 - 1) & 63];
        acc += a4.z * sW[i][(m - j0 - 2) & 63];
        acc += a4.w * sW[i][(m - j0 - 3) & 63];
      }
    }
    // reduce over jq within the wave (lane xor 16, 32 flips jq bits)
    acc += __shfl_xor(acc, 16, 64);
    acc += __shfl_xor(acc, 32, 64);
    if (jq == 0) zrow[m] = acc * (1.0f / 64.0f);
  }
  __syncthreads();

  // ---------------- phase 3: final DHT (== kC), this row's k-quarter -------
#pragma unroll
  for (int ch = 0; ch < 4; ++ch) {
    const int k = kq * 1024 + ch * 256 + t;  // covers 0..4095 over kq,ch,t
    out[row * 4097 + k] = dht4097_row(zrow, k) * (1.0f / 262208.0f);
  }
  if (kq == 3 && t == 0) {
    out[row * 4097 + 4096] = dht4097_row(zrow, 4096) * (1.0f / 262208.0f);
  }
}

// ---------------------------------------------------------------------------
// Workspace (floats): P[8192]
// ---------------------------------------------------------------------------
extern "C" void kernel_launch(void* const* d_in, const int* in_sizes, int n_in,
                              void* d_out, int out_size, void* d_ws, size_t ws_size,
                              hipStream_t stream) {
  const float* x  = (const float*)d_in[0];   // [4,16,8192]
  const float* w1 = (const float*)d_in[1];   // [16,16,64]
  float* out = (float*)d_out;                // [4,16,4097]
  float* P   = (float*)d_ws;                 // 8192 floats

  void* args[] = {(void*)&x, (void*)&w1, (void*)&out, (void*)&P};
  hipLaunchCooperativeKernel((void*)fused, dim3(256), dim3(256), args, 0,
                             stream);
}

// Round 2
// 70.593 us; speedup vs baseline: 1.4671x; 1.4671x over previous
//
#include <hip/hip_runtime.h>
#include <math.h>

#define TWO_PI 6.283185307179586f

// ---------------------------------------------------------------------------
// kA: big-DHT partials P[r][m][nh] of A[r][m] = sum_n x[r][n]*cas(2pi n m/8192)
// Grid: exactly 256 blocks (r = blk&63, mb = (blk>>6)&1, nh = blk>>7) = 1/CU.
// Wave owns 8 modes; lane owns float4 n-slices. All trig from LDS hi/lo tables.
// ---------------------------------------------------------------------------
__global__ __launch_bounds__(256) void kA(const float* __restrict__ x,
                                          float* __restrict__ P) {
  __shared__ float sH[128], cH[128], sL[64], cL[64];
  const int blk = blockIdx.x;
  const int t = threadIdx.x;

  if (t < 128) {
    float s, c;
    __sincosf((float)t * (TWO_PI / 128.0f), &s, &c);
    sH[t] = s;
    cH[t] = c;
  } else if (t < 192) {
    const int g = t - 128;
    float s, c;
    __sincosf((float)g * (TWO_PI / 8192.0f), &s, &c);
    sL[g] = s;
    cL[g] = c;
  }
  __syncthreads();

  const int r  = blk & 63;
  const int mb = (blk >> 6) & 1;
  const int nh = (blk >> 7) & 1;
  const int l  = t & 63;
  const int w  = t >> 6;
  const int mbase = mb * 32 + w * 8;
  const float* xr = x + r * 8192 + nh * 4096;

  float u[8], v[8], Cs[8], Ss[8];
  float accA[8][4];
  float accB[8][3];

#pragma unroll
  for (int q = 0; q < 8; ++q) {
    const int m = mbase + q;
    const int idx0 = ((nh * 4096 + 4 * l) * m) & 8191;
    const int h = idx0 >> 6, g = idx0 & 63;
    const float c0 = cH[h] * cL[g] - sH[h] * sL[g];
    const float s0 = sH[h] * cL[g] + cH[h] * sL[g];
    u[q] = c0 + s0;
    v[q] = c0 - s0;
    const int ih = (4 * m) & 127;  // 256*m mod 8192 lands on the hi table
    Cs[q] = cH[ih];
    Ss[q] = sH[ih];
#pragma unroll
    for (int j = 0; j < 4; ++j) accA[q][j] = 0.0f;
#pragma unroll
    for (int j = 0; j < 3; ++j) accB[q][j] = 0.0f;
  }

#pragma unroll 8
  for (int it = 0; it < 16; ++it) {
    const float4 xv = *reinterpret_cast<const float4*>(xr + it * 256 + 4 * l);
#pragma unroll
    for (int q = 0; q < 8; ++q) {
      accA[q][0] += xv.x * u[q];
      accA[q][1] += xv.y * u[q];
      accA[q][2] += xv.z * u[q];
      accA[q][3] += xv.w * u[q];
      accB[q][0] += xv.y * v[q];
      accB[q][1] += xv.z * v[q];
      accB[q][2] += xv.w * v[q];
      const float un = Cs[q] * u[q] + Ss[q] * v[q];
      const float vn = Cs[q] * v[q] - Ss[q] * u[q];
      u[q] = un;
      v[q] = vn;
    }
  }

  // combine weights cos(j*m*step), sin(j*m*step): lane (q*4+j) computes, shfl.
  float cval, sval;
  {
    const int qq = (l >> 2) & 7;
    const int jj = l & 3;
    const int jm = jj * (mbase + qq);  // <= 189 < 8192
    const int h = jm >> 6, g = jm & 63;
    cval = cH[h] * cL[g] - sH[h] * sL[g];
    sval = sH[h] * cL[g] + cH[h] * sL[g];
  }

#pragma unroll
  for (int q = 0; q < 8; ++q) {
    float acc = accA[q][0];
#pragma unroll
    for (int j = 1; j < 4; ++j) {
      const float cj = __shfl(cval, q * 4 + j, 64);
      const float sj = __shfl(sval, q * 4 + j, 64);
      acc += cj * accA[q][j] + sj * accB[q][j - 1];
    }
#pragma unroll
    for (int off = 32; off > 0; off >>= 1) acc += __shfl_xor(acc, off, 64);
    if (l == q) P[(r * 64 + (mbase + q)) * 2 + nh] = acc;
  }
}

// out-row DHT: sum_{m<64} zr[m] * cas(2*pi*m*k/4097), m = 8a+b split with
// one sincos per k, incremental weights, 8-step rotator (verbatim kC math).
__device__ __forceinline__ float dht4097_row(const float* zr, int k) {
  const float th = (float)k * (TWO_PI / 4097.0f);
  float s1, c1;
  __sincosf(th, &s1, &c1);
  float cw[8], sw[8];
  cw[0] = 1.0f; sw[0] = 0.0f;
  cw[1] = c1;   sw[1] = s1;
#pragma unroll
  for (int b = 2; b < 8; ++b) {
    cw[b] = cw[b - 1] * c1 - sw[b - 1] * s1;
    sw[b] = sw[b - 1] * c1 + cw[b - 1] * s1;
  }
  const float c8 = cw[7] * c1 - sw[7] * s1;
  const float s8 = sw[7] * c1 + cw[7] * s1;
  float A[8], B[8];
#pragma unroll
  for (int b = 0; b < 8; ++b) { A[b] = 0.0f; B[b] = 0.0f; }
  float u = 1.0f, v = 1.0f;
#pragma unroll
  for (int a = 0; a < 8; ++a) {
#pragma unroll
    for (int b = 0; b < 8; ++b) {
      const float zz = zr[a * 8 + b];
      A[b] += zz * u;
      B[b] += zz * v;
    }
    const float un = c8 * u + s8 * v;
    const float vn = c8 * v - s8 * u;
    u = un; v = vn;
  }
  float acc = 0.0f;
#pragma unroll
  for (int b = 0; b < 8; ++b) acc += cw[b] * A[b] + sw[b] * B[b];
  return acc;
}

// ---------------------------------------------------------------------------
// kBC: fused conv-theorem + final DHT. 256 blocks = (row = blk&63, kq = blk>>6).
// Each block redundantly builds its row's z[64] in LDS from P (conv is ~256
// FMA/thread — 4x redundancy is free vs a kernel boundary + z round-trip):
//   z[b,o,m] = (1/64) * sum_i sum_j A[b,i,j] * w1[i,o,(m-j)&63]
// then emits out[row][k] for its k-quarter (4 k/thread + k=4096 tail).
// No cross-block dependency on z -> plain launch, no grid sync.
// ---------------------------------------------------------------------------
__global__ __launch_bounds__(256) void kBC(const float* __restrict__ P,
                                           const float* __restrict__ w1,
                                           float* __restrict__ out) {
  __shared__ float sA[16][64];
  __shared__ float sW[16][64];
  __shared__ float zrow[64];

  const int blk = blockIdx.x;
  const int t = threadIdx.x;
  const int row = blk & 63;   // b*16 + o
  const int kq  = blk >> 6;   // k-quarter
  const int b   = row >> 4;
  const int o   = row & 15;

  for (int idx = t; idx < 1024; idx += 256) {
    const int i = idx >> 6;
    const int c = idx & 63;
    const float2 pv =
        *reinterpret_cast<const float2*>(&P[(((b * 16 + i) << 6) + c) * 2]);
    sA[i][c] = pv.x + pv.y;
    sW[i][c] = w1[((i * 16 + o) << 6) + c];
  }
  __syncthreads();

  {
    const int w  = t >> 6;    // wave = m-quarter
    const int l  = t & 63;
    const int jq = l >> 4;    // j-quarter
    const int ml = l & 15;    // local m
    const int m  = w * 16 + ml;
    float acc = 0.0f;
#pragma unroll
    for (int i = 0; i < 16; ++i) {
#pragma unroll
      for (int jb = 0; jb < 4; ++jb) {
        const int j0 = jq * 16 + jb * 4;
        const float4 a4 = *reinterpret_cast<const float4*>(&sA[i][j0]);
        acc += a4.x * sW[i][(m - j0) & 63];
        acc += a4.y * sW[i][(m - j0 - 1) & 63];
        acc += a4.z * sW[i][(m - j0 - 2) & 63];
        acc += a4.w * sW[i][(m - j0 - 3) & 63];
      }
    }
    // reduce over jq within the wave (lane xor 16, 32 flips jq bits)
    acc += __shfl_xor(acc, 16, 64);
    acc += __shfl_xor(acc, 32, 64);
    if (jq == 0) zrow[m] = acc * (1.0f / 64.0f);
  }
  __syncthreads();

  // final DHT for this row's k-quarter (all lanes read same zrow addr ->
  // LDS broadcast, conflict-free)
#pragma unroll
  for (int ch = 0; ch < 4; ++ch) {
    const int k = kq * 1024 + ch * 256 + t;  // covers 0..4095 over kq,ch,t
    out[row * 4097 + k] = dht4097_row(zrow, k) * (1.0f / 262208.0f);
  }
  if (kq == 3 && t == 0) {
    out[row * 4097 + 4096] = dht4097_row(zrow, 4096) * (1.0f / 262208.0f);
  }
}

// ---------------------------------------------------------------------------
// Workspace (floats): P[8192]
// ---------------------------------------------------------------------------
extern "C" void kernel_launch(void* const* d_in, const int* in_sizes, int n_in,
                              void* d_out, int out_size, void* d_ws, size_t ws_size,
                              hipStream_t stream) {
  const float* x  = (const float*)d_in[0];   // [4,16,8192]
  const float* w1 = (const float*)d_in[1];   // [16,16,64]
  float* out = (float*)d_out;                // [4,16,4097]
  float* P   = (float*)d_ws;                 // 8192 floats

  kA<<<256, 256, 0, stream>>>(x, P);
  kBC<<<256, 256, 0, stream>>>(P, w1, out);
}